// Round 7
// baseline (279.532 us; speedup 1.0000x reference)
//
#include <hip/hip_runtime.h>
#include <cstdint>

typedef __bf16 bf16_t;
typedef __bf16 bf16x4 __attribute__((ext_vector_type(4)));
typedef __bf16 bf16x8 __attribute__((ext_vector_type(8)));
typedef float f32x4 __attribute__((ext_vector_type(4)));

// ---- geometry constants ----
#define BT_   128
#define LTOK  197
#define CIN   768
#define CA_   384
#define TT    16
#define HH    14
#define NTOK  25088   // 128*196

__device__ __forceinline__ void gl_lds16(const void* g, void* l) {
  __builtin_amdgcn_global_load_lds(
      (const __attribute__((address_space(1))) unsigned int*)g,
      (__attribute__((address_space(3))) unsigned int*)l,
      16, 0, 0);
}

#define SBAR() do { __builtin_amdgcn_sched_barrier(0); \
                    __builtin_amdgcn_s_barrier(); \
                    __builtin_amdgcn_sched_barrier(0); } while (0)

// ---------------- prep: fold 3 convs + identity into one 3x3x3 kernel ----------------
__global__ void prep_weights_kernel(
    const float* __restrict__ c1w, const float* __restrict__ c1b,
    const float* __restrict__ c2w, const float* __restrict__ c2b,
    const float* __restrict__ c3w, const float* __restrict__ c3b,
    const float* __restrict__ projw,
    bf16_t* __restrict__ Wtb,    // [27][384]
    float* __restrict__ beff,    // [384]
    float* __restrict__ pwt) {   // [3][384]
  int a = blockIdx.x * blockDim.x + threadIdx.x;
  if (a >= CA_) return;
  for (int dt = 0; dt < 3; dt++)
    for (int dh = 0; dh < 3; dh++)
      for (int dw = 0; dw < 3; dw++) {
        float v = c3w[a*27 + dt*9 + dh*3 + dw];
        if (dh == 1 && dw == 1) v += c1w[a*3 + dt];
        if (dt == 1)            v += c2w[a*9 + dh*3 + dw];
        v *= (1.0f/3.0f);
        if (dt == 1 && dh == 1 && dw == 1) v += 1.0f;   // + identity
        Wtb[((dt*3+dh)*3+dw)*CA_ + a] = (bf16_t)v;
      }
  beff[a] = (c1b[a] + c2b[a] + c3b[a]) * (1.0f/3.0f);
  pwt[0*CA_ + a] = projw[a*3 + 0];
  pwt[1*CA_ + a] = projw[a*3 + 1];
  pwt[2*CA_ + a] = projw[a*3 + 2];
}

// ---------------- convert: W->bf16, x token rows -> bf16 xb (compact), CLS rows -> out ----
__global__ __launch_bounds__(256) void convert_w_kernel(
    const float* __restrict__ fc1w, const float* __restrict__ fc2w,
    const float* __restrict__ x, float* __restrict__ out,
    bf16_t* __restrict__ W1, bf16_t* __restrict__ W2,
    bf16_t* __restrict__ xb) {
  const int NW1 = CA_*CIN/4;        // 73728
  const int NW2 = CIN*CA_/4;        // 73728
  const int NX  = BT_*LTOK*CIN/4;   // 4841472
  const int total = NW1 + NW2 + NX;
  for (int i = blockIdx.x*256 + threadIdx.x; i < total; i += gridDim.x*256) {
    if (i < NW1) {
      float4 v = ((const float4*)fc1w)[i];
      bf16x4 b; b[0]=(bf16_t)v.x; b[1]=(bf16_t)v.y; b[2]=(bf16_t)v.z; b[3]=(bf16_t)v.w;
      *(bf16x4*)(W1 + (size_t)i*4) = b;
    } else if (i < NW1 + NW2) {
      int j = i - NW1;
      float4 v = ((const float4*)fc2w)[j];
      bf16x4 b; b[0]=(bf16_t)v.x; b[1]=(bf16_t)v.y; b[2]=(bf16_t)v.z; b[3]=(bf16_t)v.w;
      *(bf16x4*)(W2 + (size_t)j*4) = b;
    } else {
      int j = i - NW1 - NW2;        // float4 index into x
      int row = j / 192;            // 192 float4 per 768-ch row
      int c4  = j - row*192;
      int l   = row % 197;
      float4 v = ((const float4*)x)[(size_t)j];
      if (l == 0) {
        ((float4*)out)[(size_t)j] = v;   // CLS residual passthrough
      } else {
        int tok = (row/197)*196 + (l - 1);
        bf16x4 b; b[0]=(bf16_t)v.x; b[1]=(bf16_t)v.y; b[2]=(bf16_t)v.z; b[3]=(bf16_t)v.w;
        *(bf16x4*)(xb + (size_t)tok*CIN + c4*4) = b;
      }
    }
  }
}

// ---------------- GEMM1: H0[tok,a] = bf16( xb[tok,:] . fc1_w[a,:] + fc1_b[a] ) ----------------
// 128x128 tile, all-gl_lds staging, 3-buffer prefetch-distance-2, counted vmcnt
// (never 0 in steady state), one raw fenced s_barrier per K-step. 48 KB LDS -> 3 blocks/CU.
__global__ __launch_bounds__(256) void gemm1_kernel(
    const bf16_t* __restrict__ xb, const bf16_t* __restrict__ W1,
    const float* __restrict__ fc1b, bf16_t* __restrict__ H0) {
  __shared__ bf16_t Alds[3][128*32];   // 8 KB each
  __shared__ bf16_t Blds[3][128*32];   // 8 KB each
  const int tid  = threadIdx.x;
  const int lane = tid & 63;
  const int wave = tid >> 6;
  const int bm = blockIdx.x, bn = blockIdx.y;

  const bf16_t* asrc0 = xb + (size_t)(bm*128 + (tid>>2))*CIN + (tid&3)*8;
  const bf16_t* asrc1 = asrc0 + (size_t)64*CIN;
  const bf16_t* bsrc0 = W1 + (size_t)(bn*128 + (tid>>2))*CIN + (tid&3)*8;
  const bf16_t* bsrc1 = bsrc0 + (size_t)64*CIN;
  const int off0 = tid*8;
  const int off1 = (tid+256)*8;

  const int quad = lane >> 4;
  const int r16  = lane & 15;
  const int wm = (wave >> 1) * 64;
  const int wn = (wave & 1) * 64;

  f32x4 acc[4][4] = {};

#define G1_G(S, K) do { \
    gl_lds16(asrc0 + (K), &Alds[S][off0]); \
    gl_lds16(asrc1 + (K), &Alds[S][off1]); \
    gl_lds16(bsrc0 + (K), &Blds[S][off0]); \
    gl_lds16(bsrc1 + (K), &Blds[S][off1]); } while (0)
#define G1_M(S) do { bf16x8 af_[4], bf_[4]; \
    _Pragma("unroll") \
    for (int mt = 0; mt < 4; mt++) \
      af_[mt] = *(const bf16x8*)&Alds[S][(wm + mt*16 + r16)*32 + quad*8]; \
    _Pragma("unroll") \
    for (int nt = 0; nt < 4; nt++) \
      bf_[nt] = *(const bf16x8*)&Blds[S][(wn + nt*16 + r16)*32 + quad*8]; \
    _Pragma("unroll") \
    for (int mt = 0; mt < 4; mt++) \
      _Pragma("unroll") \
      for (int nt = 0; nt < 4; nt++) \
        acc[mt][nt] = __builtin_amdgcn_mfma_f32_16x16x32_bf16(af_[mt], bf_[nt], acc[mt][nt], 0, 0, 0); \
  } while (0)

  // prologue: sets 0,1 in flight; wait for set 0 only
  G1_G(0, 0);
  G1_G(1, 32);
  asm volatile("s_waitcnt vmcnt(4)" ::: "memory");
  SBAR();

  // main: i = 0..20 (issues sets 2..22)
  #pragma unroll 1
  for (int ii = 0; ii < 7; ii++) {
    #pragma unroll
    for (int j = 0; j < 3; j++) {
      const int i = ii*3 + j;             // buffer = j
      G1_G((j + 2) % 3, (i + 2)*32);      // set i+2
      G1_M(j);                            // compute set i
      asm volatile("s_waitcnt vmcnt(4)" ::: "memory");  // set i+1 landed
      SBAR();
    }
  }
  // i=21 (buf 0): issue set 23
  G1_G(2, 23*32);
  G1_M(0);
  asm volatile("s_waitcnt vmcnt(4)" ::: "memory");
  SBAR();
  // i=22 (buf 1): drain set 23
  G1_M(1);
  asm volatile("s_waitcnt vmcnt(0)" ::: "memory");
  SBAR();
  // i=23 (buf 2)
  G1_M(2);

  #pragma unroll
  for (int nt = 0; nt < 4; nt++) {
    const int col = bn*128 + wn + nt*16 + r16;
    const float bias = fc1b[col];
    #pragma unroll
    for (int mt = 0; mt < 4; mt++) {
      const int row0 = bm*128 + wm + mt*16 + quad*4;
      #pragma unroll
      for (int rg = 0; rg < 4; rg++)
        H0[(size_t)(row0 + rg)*CA_ + col] = (bf16_t)(acc[mt][nt][rg] + bias);
    }
  }
#undef G1_G
#undef G1_M
}

// ---------------- fused conv v4: register-local temporal scatter, XCD-swizzled ----------------
__global__ __launch_bounds__(192) void conv_kernel(
    const bf16_t* __restrict__ H0,
    const bf16_t* __restrict__ Wtb,   // [27][384] bf16
    const float* __restrict__ beff,   // [384]
    const float* __restrict__ pwt,    // [3][384]
    const float* __restrict__ pb,     // [384]
    bf16_t* __restrict__ Z) {
  __shared__ bf16_t Wlds[27*CA_];     // 20736 B
  __shared__ float  ybuf[2][2][CA_];  // 6144 B

  const int tid = threadIdx.x;
  {
    const uint4* src = (const uint4*)Wtb;
    uint4* dst = (uint4*)Wlds;
    #pragma unroll
    for (int i = 0; i < 7; i++) {
      int idx = tid + i*192;
      if (idx < 27*CA_/8) dst[idx] = src[idx];   // 1296 x 16B
    }
  }

  const int blk  = blockIdx.x;       // 0..783
  const int b    = blk & 7;
  const int pair = blk >> 3;         // 0..97
  const int cg   = tid % 48;
  const int ct   = tid / 48;         // 0..3
  const int col  = ct >> 1;
  const int th   = ct & 1;
  const int hw   = pair*2 + col;     // 0..195
  const int h    = hw / HH, w = hw % HH;
  const int c0   = cg * 8;
  const int t0   = th * 8;

  // init y with effective bias
  float y[8][8];
  {
    f32x4 bv0 = *(const f32x4*)(beff + c0);
    f32x4 bv1 = *(const f32x4*)(beff + c0 + 4);
    #pragma unroll
    for (int i = 0; i < 8; i++) {
      #pragma unroll
      for (int c = 0; c < 4; c++) { y[i][c] = bv0[c]; y[i][c+4] = bv1[c]; }
    }
  }

  __syncthreads();   // Wlds ready

  const size_t rowstride = (size_t)196*CA_;   // elements per t-step
  const bf16_t* base_t0 = H0 + ((size_t)(b*TT + t0)*196)*CA_ + c0;
  const int tau_e_off = th ? -1 : 8;          // the one extra valid tau (relative to t0)

  for (int j = 0; j < 9; j++) {
    const int dh = j / 3, dw = j - dh*3;
    const int h2 = h + dh - 1, w2 = w + dw - 1;
    const bool ok = ((unsigned)h2 < HH) && ((unsigned)w2 < HH);
    const int sp = ok ? (h2*HH + w2) : hw;    // clamped, always in-bounds
    const float m = ok ? 1.0f : 0.0f;

    const bf16x8 wv0 = *(const bf16x8*)&Wlds[(0*9+j)*CA_ + c0];
    const bf16x8 wv1 = *(const bf16x8*)&Wlds[(1*9+j)*CA_ + c0];
    const bf16x8 wv2 = *(const bf16x8*)&Wlds[(2*9+j)*CA_ + c0];
    float mw0[8], mw1[8], mw2[8];
    #pragma unroll
    for (int c = 0; c < 8; c++) {
      mw0[c] = m * (float)wv0[c];
      mw1[c] = m * (float)wv1[c];
      mw2[c] = m * (float)wv2[c];
    }

    const bf16_t* tp = base_t0 + (size_t)sp*CA_;
    bf16x8 gv[8];
    #pragma unroll
    for (int i = 0; i < 8; i++)
      gv[i] = *(const bf16x8*)(tp + (ptrdiff_t)i*(ptrdiff_t)rowstride);
    const bf16x8 ge = *(const bf16x8*)(tp + (ptrdiff_t)tau_e_off*(ptrdiff_t)rowstride);

    // interior taus: tau = t0+i contributes to y[i-1] (w2), y[i] (w1), y[i+1] (w0)
    #pragma unroll
    for (int i = 0; i < 8; i++) {
      float gf[8];
      #pragma unroll
      for (int c = 0; c < 8; c++) gf[c] = (float)gv[i][c];
      #pragma unroll
      for (int c = 0; c < 8; c++) y[i][c] += gf[c]*mw1[c];
      if (i > 0) {
        #pragma unroll
        for (int c = 0; c < 8; c++) y[i-1][c] += gf[c]*mw2[c];
      }
      if (i < 7) {
        #pragma unroll
        for (int c = 0; c < 8; c++) y[i+1][c] += gf[c]*mw0[c];
      }
    }
    // edge tau: th=0 -> tau=t0+8 feeds y[7] via w2 ; th=1 -> tau=t0-1 feeds y[0] via w0
    {
      float gf[8];
      #pragma unroll
      for (int c = 0; c < 8; c++) gf[c] = (float)ge[c];
      if (th) {
        #pragma unroll
        for (int c = 0; c < 8; c++) y[0][c] += gf[c]*mw0[c];
      } else {
        #pragma unroll
        for (int c = 0; c < 8; c++) y[7][c] += gf[c]*mw2[c];
      }
    }
  }

  // exchange the boundary y between t-halves (for the temporal proj)
  #pragma unroll
  for (int c = 0; c < 8; c++) ybuf[col][th][c0+c] = th ? y[0][c] : y[7][c];
  __syncthreads();
  float yedge[8];
  #pragma unroll
  for (int c = 0; c < 8; c++) yedge[c] = ybuf[col][1-th][c0+c];

  // proj weights
  float p0[8], p1[8], p2[8], pbv[8];
  {
    f32x4 a0 = *(const f32x4*)(pwt + 0*CA_ + c0), a1 = *(const f32x4*)(pwt + 0*CA_ + c0 + 4);
    f32x4 b0 = *(const f32x4*)(pwt + 1*CA_ + c0), b1 = *(const f32x4*)(pwt + 1*CA_ + c0 + 4);
    f32x4 d0 = *(const f32x4*)(pwt + 2*CA_ + c0), d1 = *(const f32x4*)(pwt + 2*CA_ + c0 + 4);
    f32x4 e0 = *(const f32x4*)(pb + c0),          e1 = *(const f32x4*)(pb + c0 + 4);
    #pragma unroll
    for (int c = 0; c < 4; c++) {
      p0[c]=a0[c]; p0[c+4]=a1[c];
      p1[c]=b0[c]; p1[c+4]=b1[c];
      p2[c]=d0[c]; p2[c+4]=d1[c];
      pbv[c]=e0[c]; pbv[c+4]=e1[c];
    }
  }

  bf16_t* zbase = Z + ((size_t)(b*TT + t0)*196 + hw)*CA_ + c0;
  #pragma unroll
  for (int i = 0; i < 8; i++) {
    bf16x8 zo;
    #pragma unroll
    for (int c = 0; c < 8; c++) {
      const float ym = (i > 0) ? y[i-1][c] : (th ? yedge[c] : 0.f);
      const float yp = (i < 7) ? y[i+1][c] : (th ? 0.f : yedge[c]);
      const float z  = y[i][c] + pbv[c] + p0[c]*ym + p1[c]*y[i][c] + p2[c]*yp;
      zo[c] = (bf16_t)z;
    }
    *(bf16x8*)(zbase + (size_t)i*rowstride) = zo;
  }
}

// ---------------- GEMM2: out[xrow,c] = x[xrow,c] + Z[tok,:] . fc2_w[c,:] + fc2_b[c] ----------------
// Same pipelined structure as gemm1: K=384, 12 steps, 3 buffers, counted vmcnt.
__global__ __launch_bounds__(256) void gemm2_kernel(
    const bf16_t* __restrict__ Z, const bf16_t* __restrict__ W2,
    const float* __restrict__ fc2b, const float* __restrict__ x,
    float* __restrict__ out) {
  __shared__ bf16_t Alds[3][128*32];
  __shared__ bf16_t Blds[3][128*32];
  const int tid  = threadIdx.x;
  const int lane = tid & 63;
  const int wave = tid >> 6;
  const int bm = blockIdx.x, bn = blockIdx.y;

  const bf16_t* asrc0 = Z  + (size_t)(bm*128 + (tid>>2))*CA_ + (tid&3)*8;
  const bf16_t* asrc1 = asrc0 + (size_t)64*CA_;
  const bf16_t* bsrc0 = W2 + (size_t)(bn*128 + (tid>>2))*CA_ + (tid&3)*8;
  const bf16_t* bsrc1 = bsrc0 + (size_t)64*CA_;
  const int off0 = tid*8;
  const int off1 = (tid+256)*8;

  const int quad = lane >> 4;
  const int r16  = lane & 15;
  const int wm = (wave >> 1) * 64;
  const int wn = (wave & 1) * 64;

  f32x4 acc[4][4] = {};

#define G2_G(S, K) do { \
    gl_lds16(asrc0 + (K), &Alds[S][off0]); \
    gl_lds16(asrc1 + (K), &Alds[S][off1]); \
    gl_lds16(bsrc0 + (K), &Blds[S][off0]); \
    gl_lds16(bsrc1 + (K), &Blds[S][off1]); } while (0)
#define G2_M(S) do { bf16x8 af_[4], bf_[4]; \
    _Pragma("unroll") \
    for (int mt = 0; mt < 4; mt++) \
      af_[mt] = *(const bf16x8*)&Alds[S][(wm + mt*16 + r16)*32 + quad*8]; \
    _Pragma("unroll") \
    for (int nt = 0; nt < 4; nt++) \
      bf_[nt] = *(const bf16x8*)&Blds[S][(wn + nt*16 + r16)*32 + quad*8]; \
    _Pragma("unroll") \
    for (int mt = 0; mt < 4; mt++) \
      _Pragma("unroll") \
      for (int nt = 0; nt < 4; nt++) \
        acc[mt][nt] = __builtin_amdgcn_mfma_f32_16x16x32_bf16(af_[mt], bf_[nt], acc[mt][nt], 0, 0, 0); \
  } while (0)

  // prologue: sets 0,1
  G2_G(0, 0);
  G2_G(1, 32);
  asm volatile("s_waitcnt vmcnt(4)" ::: "memory");
  SBAR();

  // main: i = 0..8 (issues sets 2..10)
  #pragma unroll 1
  for (int ii = 0; ii < 3; ii++) {
    #pragma unroll
    for (int j = 0; j < 3; j++) {
      const int i = ii*3 + j;             // buffer = j
      G2_G((j + 2) % 3, (i + 2)*32);
      G2_M(j);
      asm volatile("s_waitcnt vmcnt(4)" ::: "memory");
      SBAR();
    }
  }
  // i=9 (buf 0): issue set 11
  G2_G(2, 11*32);
  G2_M(0);
  asm volatile("s_waitcnt vmcnt(4)" ::: "memory");
  SBAR();
  // i=10 (buf 1): drain set 11
  G2_M(1);
  asm volatile("s_waitcnt vmcnt(0)" ::: "memory");
  SBAR();
  // i=11 (buf 2)
  G2_M(2);

  #pragma unroll
  for (int nt = 0; nt < 4; nt++) {
    const int col = bn*128 + wn + nt*16 + r16;
    const float bias = fc2b[col];
    #pragma unroll
    for (int mt = 0; mt < 4; mt++) {
      #pragma unroll
      for (int rg = 0; rg < 4; rg++) {
        const int tok = bm*128 + wm + mt*16 + quad*4 + rg;
        const int bt  = tok / 196;
        const size_t o = (size_t)(tok + bt + 1)*CIN + col;
        out[o] = x[o] + acc[mt][nt][rg] + bias;
      }
    }
  }
#undef G2_G
#undef G2_M
}

extern "C" void kernel_launch(void* const* d_in, const int* in_sizes, int n_in,
                              void* d_out, int out_size, void* d_ws, size_t ws_size,
                              hipStream_t stream) {
  (void)in_sizes; (void)n_in; (void)out_size; (void)ws_size;
  const float* x    = (const float*)d_in[0];
  const float* fc1w = (const float*)d_in[1];
  const float* fc1b = (const float*)d_in[2];
  const float* c1w  = (const float*)d_in[3];
  const float* c1b  = (const float*)d_in[4];
  const float* c2w  = (const float*)d_in[5];
  const float* c2b  = (const float*)d_in[6];
  const float* c3w  = (const float*)d_in[7];
  const float* c3b  = (const float*)d_in[8];
  const float* pw   = (const float*)d_in[9];
  const float* pb   = (const float*)d_in[10];
  const float* fc2w = (const float*)d_in[11];
  const float* fc2b = (const float*)d_in[12];
  float* out = (float*)d_out;

  char* ws = (char*)d_ws;
  bf16_t* W1   = (bf16_t*)(ws);                    // 589824
  bf16_t* W2   = (bf16_t*)(ws + 589824);           // 589824
  bf16_t* Wtb  = (bf16_t*)(ws + 1179648);          // 20736
  float*  beff = (float*) (ws + 1200384);          // 1536
  float*  pwt  = (float*) (ws + 1201920);          // 4608
  bf16_t* xb   = (bf16_t*)(ws + 1206528);          // 38535168 (dead after gemm1)
  bf16_t* Z    = (bf16_t*)(ws + 1206528);          // 19267584 (aliases xb; born in conv)
  bf16_t* H0   = (bf16_t*)(ws + 39741696);         // 19267584 -> total 59009280 bytes

  prep_weights_kernel<<<dim3(2), dim3(192), 0, stream>>>(
      c1w, c1b, c2w, c2b, c3w, c3b, pw, Wtb, beff, pwt);
  convert_w_kernel<<<dim3(4096), dim3(256), 0, stream>>>(fc1w, fc2w, x, out, W1, W2, xb);
  gemm1_kernel<<<dim3(196, 3), dim3(256), 0, stream>>>(xb, W1, fc1b, H0);
  conv_kernel<<<dim3(784), dim3(192), 0, stream>>>(H0, Wtb, beff, pwt, pb, Z);
  gemm2_kernel<<<dim3(196, 6), dim3(256), 0, stream>>>(Z, W2, fc2b, x, out);
}

// Round 8
// 266.318 us; speedup vs baseline: 1.0496x; 1.0496x over previous
//
#include <hip/hip_runtime.h>
#include <cstdint>

typedef __bf16 bf16_t;
typedef __bf16 bf16x4 __attribute__((ext_vector_type(4)));
typedef __bf16 bf16x8 __attribute__((ext_vector_type(8)));
typedef float f32x4 __attribute__((ext_vector_type(4)));

// ---- geometry constants ----
#define BT_   128
#define LTOK  197
#define CIN   768
#define CA_   384
#define TT    16
#define HH    14
#define NTOK  25088   // 128*196

__device__ __forceinline__ void gl_lds16(const void* g, void* l) {
  __builtin_amdgcn_global_load_lds(
      (const __attribute__((address_space(1))) unsigned int*)g,
      (__attribute__((address_space(3))) unsigned int*)l,
      16, 0, 0);
}

#define SBAR() do { __builtin_amdgcn_sched_barrier(0); \
                    __builtin_amdgcn_s_barrier(); \
                    __builtin_amdgcn_sched_barrier(0); } while (0)

// ---------------- prep: fold 3 convs + identity into one 3x3x3 kernel ----------------
__global__ void prep_weights_kernel(
    const float* __restrict__ c1w, const float* __restrict__ c1b,
    const float* __restrict__ c2w, const float* __restrict__ c2b,
    const float* __restrict__ c3w, const float* __restrict__ c3b,
    const float* __restrict__ projw,
    bf16_t* __restrict__ Wtb,    // [27][384]
    float* __restrict__ beff,    // [384]
    float* __restrict__ pwt) {   // [3][384]
  int a = blockIdx.x * blockDim.x + threadIdx.x;
  if (a >= CA_) return;
  for (int dt = 0; dt < 3; dt++)
    for (int dh = 0; dh < 3; dh++)
      for (int dw = 0; dw < 3; dw++) {
        float v = c3w[a*27 + dt*9 + dh*3 + dw];
        if (dh == 1 && dw == 1) v += c1w[a*3 + dt];
        if (dt == 1)            v += c2w[a*9 + dh*3 + dw];
        v *= (1.0f/3.0f);
        if (dt == 1 && dh == 1 && dw == 1) v += 1.0f;   // + identity
        Wtb[((dt*3+dh)*3+dw)*CA_ + a] = (bf16_t)v;
      }
  beff[a] = (c1b[a] + c2b[a] + c3b[a]) * (1.0f/3.0f);
  pwt[0*CA_ + a] = projw[a*3 + 0];
  pwt[1*CA_ + a] = projw[a*3 + 1];
  pwt[2*CA_ + a] = projw[a*3 + 2];
}

// ---------------- convert: W -> bf16 FRAG-LINEAR, x token rows -> bf16 xb, CLS rows -> out ----
// Frag layout (r5-verified): frag f holds a 16-col x 32-k B tile; lane l supplies
// B[col = cb*16 + (l&15)][k = ch*32 + (l>>4)*8 + j], j=0..7 -> elem f*512 + l*8 + j.
// W1f: f = ch*24 + cb (ch<24, cb<24).  W2f: f = ch*48 + cb (ch<12, cb<48).
__global__ __launch_bounds__(256) void convert_w_kernel(
    const float* __restrict__ fc1w, const float* __restrict__ fc2w,
    const float* __restrict__ x, float* __restrict__ out,
    bf16_t* __restrict__ W1f, bf16_t* __restrict__ W2f,
    bf16_t* __restrict__ xb) {
  const int NW1 = CA_*CIN/4;        // 73728 float4 units
  const int NW2 = CIN*CA_/4;        // 73728
  const int NX  = BT_*LTOK*CIN/4;   // 4841472
  const int total = NW1 + NW2 + NX;
  for (int i = blockIdx.x*256 + threadIdx.x; i < total; i += gridDim.x*256) {
    if (i < NW1) {
      int e = i*4, f = e >> 9, t = e & 511, l = t >> 3, jb = t & 7;
      int ch = f / 24, cb = f - ch*24;
      int col = cb*16 + (l & 15);
      int k   = ch*32 + ((l >> 4) << 3) + jb;
      float4 v = *(const float4*)(fc1w + (size_t)col*CIN + k);
      bf16x4 b; b[0]=(bf16_t)v.x; b[1]=(bf16_t)v.y; b[2]=(bf16_t)v.z; b[3]=(bf16_t)v.w;
      *(bf16x4*)(W1f + e) = b;
    } else if (i < NW1 + NW2) {
      int e = (i - NW1)*4, f = e >> 9, t = e & 511, l = t >> 3, jb = t & 7;
      int ch = f / 48, cb = f - ch*48;
      int col = cb*16 + (l & 15);
      int k   = ch*32 + ((l >> 4) << 3) + jb;
      float4 v = *(const float4*)(fc2w + (size_t)col*CA_ + k);
      bf16x4 b; b[0]=(bf16_t)v.x; b[1]=(bf16_t)v.y; b[2]=(bf16_t)v.z; b[3]=(bf16_t)v.w;
      *(bf16x4*)(W2f + e) = b;
    } else {
      int j = i - NW1 - NW2;        // float4 index into x
      int row = j / 192;            // 192 float4 per 768-ch row
      int c4  = j - row*192;
      int l   = row % 197;
      float4 v = ((const float4*)x)[(size_t)j];
      if (l == 0) {
        ((float4*)out)[(size_t)j] = v;   // CLS residual passthrough
      } else {
        int tok = (row/197)*196 + (l - 1);
        bf16x4 b; b[0]=(bf16_t)v.x; b[1]=(bf16_t)v.y; b[2]=(bf16_t)v.z; b[3]=(bf16_t)v.w;
        *(bf16x4*)(xb + (size_t)tok*CIN + c4*4) = b;
      }
    }
  }
}

// ---------------- GEMM1: H0[tok,a] = bf16( xb[tok,:] . fc1_w[a,:] + fc1_b[a] ) ----------------
// A-only LDS (3 x 8KB, prefetch distance 2, counted vmcnt); B frag-linear direct from L2
// into registers, issued FIRST each step (sched_barrier-pinned) so the compiler's
// wait-for-B retires gl_lds(i+1) in order WITHOUT draining gl_lds(i+2).
__global__ __launch_bounds__(256) void gemm1_kernel(
    const bf16_t* __restrict__ xb, const bf16_t* __restrict__ W1f,
    const float* __restrict__ fc1b, bf16_t* __restrict__ H0) {
  __shared__ bf16_t Alds[3][4096];   // 8 KB each: [128][32]
  const int tid  = threadIdx.x;
  const int lane = tid & 63;
  const int wave = tid >> 6;
  const int bm = blockIdx.x, bn = blockIdx.y;

  const bf16_t* asrc0 = xb + (size_t)(bm*128 + (tid>>2))*CIN + (tid&3)*8;
  const bf16_t* asrc1 = asrc0 + (size_t)64*CIN;
  const int off0 = tid*8;
  const int off1 = tid*8 + 2048;

  const int quad = lane >> 4;
  const int r16  = lane & 15;
  const int wm = (wave >> 1) * 64;
  const int wn = (wave & 1) * 64;

  // B frag base: f = ch*24 + (bn*8 + (wave&1)*4 + nt)
  const bf16_t* wb = W1f + ((size_t)(bn*8 + (wave & 1)*4))*512 + lane*8;

  f32x4 acc[4][4] = {};

#define G1_A(S, K) do { \
    gl_lds16(asrc0 + (K), &Alds[S][off0]); \
    gl_lds16(asrc1 + (K), &Alds[S][off1]); } while (0)
#define G1_B(CH) do { \
    bfr[0] = *(const bf16x8*)(wb + (size_t)((CH)*24 + 0)*512); \
    bfr[1] = *(const bf16x8*)(wb + (size_t)((CH)*24 + 1)*512); \
    bfr[2] = *(const bf16x8*)(wb + (size_t)((CH)*24 + 2)*512); \
    bfr[3] = *(const bf16x8*)(wb + (size_t)((CH)*24 + 3)*512); } while (0)
#define G1_M(S) do { bf16x8 af_[4]; \
    _Pragma("unroll") \
    for (int mt = 0; mt < 4; mt++) \
      af_[mt] = *(const bf16x8*)&Alds[S][(wm + mt*16 + r16)*32 + quad*8]; \
    _Pragma("unroll") \
    for (int mt = 0; mt < 4; mt++) \
      _Pragma("unroll") \
      for (int nt = 0; nt < 4; nt++) \
        acc[mt][nt] = __builtin_amdgcn_mfma_f32_16x16x32_bf16(af_[mt], bfr[nt], acc[mt][nt], 0, 0, 0); \
  } while (0)

  // prologue: A sets 0,1 in flight; wait set 0 only
  G1_A(0, 0);
  G1_A(1, 32);
  asm volatile("s_waitcnt vmcnt(2)" ::: "memory");
  SBAR();

  // main: i = 0..20 (issues A sets 2..22)
  #pragma unroll 1
  for (int ii = 0; ii < 7; ii++) {
    #pragma unroll
    for (int j = 0; j < 3; j++) {
      const int i = ii*3 + j;                  // buffer = j
      bf16x8 bfr[4];
      G1_B(i);                                 // B first (in-order retire carrier)
      __builtin_amdgcn_sched_barrier(0);
      G1_A((j + 2) % 3, (i + 2)*32);           // then A set i+2
      G1_M(j);                                 // compiler waits B(i) -> retires gl(i+1)
      asm volatile("s_waitcnt vmcnt(2)" ::: "memory");   // safety: only gl(i+2) may remain
      SBAR();
    }
  }
  { // i=21 (buf 0): issue A set 23
    bf16x8 bfr[4];
    G1_B(21);
    __builtin_amdgcn_sched_barrier(0);
    G1_A(2, 23*32);
    G1_M(0);
    asm volatile("s_waitcnt vmcnt(2)" ::: "memory");
    SBAR();
  }
  { // i=22 (buf 1)
    bf16x8 bfr[4];
    G1_B(22);
    __builtin_amdgcn_sched_barrier(0);
    G1_M(1);
    asm volatile("s_waitcnt vmcnt(0)" ::: "memory");
    SBAR();
  }
  { // i=23 (buf 2)
    bf16x8 bfr[4];
    G1_B(23);
    G1_M(2);
  }

  #pragma unroll
  for (int nt = 0; nt < 4; nt++) {
    const int col = bn*128 + wn + nt*16 + r16;
    const float bias = fc1b[col];
    #pragma unroll
    for (int mt = 0; mt < 4; mt++) {
      const int row0 = bm*128 + wm + mt*16 + quad*4;
      #pragma unroll
      for (int rg = 0; rg < 4; rg++)
        H0[(size_t)(row0 + rg)*CA_ + col] = (bf16_t)(acc[mt][nt][rg] + bias);
    }
  }
#undef G1_A
#undef G1_B
#undef G1_M
}

// ---------------- fused conv v4: register-local temporal scatter, XCD-swizzled ----------------
__global__ __launch_bounds__(192) void conv_kernel(
    const bf16_t* __restrict__ H0,
    const bf16_t* __restrict__ Wtb,   // [27][384] bf16
    const float* __restrict__ beff,   // [384]
    const float* __restrict__ pwt,    // [3][384]
    const float* __restrict__ pb,     // [384]
    bf16_t* __restrict__ Z) {
  __shared__ bf16_t Wlds[27*CA_];     // 20736 B
  __shared__ float  ybuf[2][2][CA_];  // 6144 B

  const int tid = threadIdx.x;
  {
    const uint4* src = (const uint4*)Wtb;
    uint4* dst = (uint4*)Wlds;
    #pragma unroll
    for (int i = 0; i < 7; i++) {
      int idx = tid + i*192;
      if (idx < 27*CA_/8) dst[idx] = src[idx];   // 1296 x 16B
    }
  }

  const int blk  = blockIdx.x;       // 0..783
  const int b    = blk & 7;
  const int pair = blk >> 3;         // 0..97
  const int cg   = tid % 48;
  const int ct   = tid / 48;         // 0..3
  const int col  = ct >> 1;
  const int th   = ct & 1;
  const int hw   = pair*2 + col;     // 0..195
  const int h    = hw / HH, w = hw % HH;
  const int c0   = cg * 8;
  const int t0   = th * 8;

  // init y with effective bias
  float y[8][8];
  {
    f32x4 bv0 = *(const f32x4*)(beff + c0);
    f32x4 bv1 = *(const f32x4*)(beff + c0 + 4);
    #pragma unroll
    for (int i = 0; i < 8; i++) {
      #pragma unroll
      for (int c = 0; c < 4; c++) { y[i][c] = bv0[c]; y[i][c+4] = bv1[c]; }
    }
  }

  __syncthreads();   // Wlds ready

  const size_t rowstride = (size_t)196*CA_;   // elements per t-step
  const bf16_t* base_t0 = H0 + ((size_t)(b*TT + t0)*196)*CA_ + c0;
  const int tau_e_off = th ? -1 : 8;          // the one extra valid tau (relative to t0)

  for (int j = 0; j < 9; j++) {
    const int dh = j / 3, dw = j - dh*3;
    const int h2 = h + dh - 1, w2 = w + dw - 1;
    const bool ok = ((unsigned)h2 < HH) && ((unsigned)w2 < HH);
    const int sp = ok ? (h2*HH + w2) : hw;    // clamped, always in-bounds
    const float m = ok ? 1.0f : 0.0f;

    const bf16x8 wv0 = *(const bf16x8*)&Wlds[(0*9+j)*CA_ + c0];
    const bf16x8 wv1 = *(const bf16x8*)&Wlds[(1*9+j)*CA_ + c0];
    const bf16x8 wv2 = *(const bf16x8*)&Wlds[(2*9+j)*CA_ + c0];
    float mw0[8], mw1[8], mw2[8];
    #pragma unroll
    for (int c = 0; c < 8; c++) {
      mw0[c] = m * (float)wv0[c];
      mw1[c] = m * (float)wv1[c];
      mw2[c] = m * (float)wv2[c];
    }

    const bf16_t* tp = base_t0 + (size_t)sp*CA_;
    bf16x8 gv[8];
    #pragma unroll
    for (int i = 0; i < 8; i++)
      gv[i] = *(const bf16x8*)(tp + (ptrdiff_t)i*(ptrdiff_t)rowstride);
    const bf16x8 ge = *(const bf16x8*)(tp + (ptrdiff_t)tau_e_off*(ptrdiff_t)rowstride);

    // interior taus: tau = t0+i contributes to y[i-1] (w2), y[i] (w1), y[i+1] (w0)
    #pragma unroll
    for (int i = 0; i < 8; i++) {
      float gf[8];
      #pragma unroll
      for (int c = 0; c < 8; c++) gf[c] = (float)gv[i][c];
      #pragma unroll
      for (int c = 0; c < 8; c++) y[i][c] += gf[c]*mw1[c];
      if (i > 0) {
        #pragma unroll
        for (int c = 0; c < 8; c++) y[i-1][c] += gf[c]*mw2[c];
      }
      if (i < 7) {
        #pragma unroll
        for (int c = 0; c < 8; c++) y[i+1][c] += gf[c]*mw0[c];
      }
    }
    // edge tau: th=0 -> tau=t0+8 feeds y[7] via w2 ; th=1 -> tau=t0-1 feeds y[0] via w0
    {
      float gf[8];
      #pragma unroll
      for (int c = 0; c < 8; c++) gf[c] = (float)ge[c];
      if (th) {
        #pragma unroll
        for (int c = 0; c < 8; c++) y[0][c] += gf[c]*mw0[c];
      } else {
        #pragma unroll
        for (int c = 0; c < 8; c++) y[7][c] += gf[c]*mw2[c];
      }
    }
  }

  // exchange the boundary y between t-halves (for the temporal proj)
  #pragma unroll
  for (int c = 0; c < 8; c++) ybuf[col][th][c0+c] = th ? y[0][c] : y[7][c];
  __syncthreads();
  float yedge[8];
  #pragma unroll
  for (int c = 0; c < 8; c++) yedge[c] = ybuf[col][1-th][c0+c];

  // proj weights
  float p0[8], p1[8], p2[8], pbv[8];
  {
    f32x4 a0 = *(const f32x4*)(pwt + 0*CA_ + c0), a1 = *(const f32x4*)(pwt + 0*CA_ + c0 + 4);
    f32x4 b0 = *(const f32x4*)(pwt + 1*CA_ + c0), b1 = *(const f32x4*)(pwt + 1*CA_ + c0 + 4);
    f32x4 d0 = *(const f32x4*)(pwt + 2*CA_ + c0), d1 = *(const f32x4*)(pwt + 2*CA_ + c0 + 4);
    f32x4 e0 = *(const f32x4*)(pb + c0),          e1 = *(const f32x4*)(pb + c0 + 4);
    #pragma unroll
    for (int c = 0; c < 4; c++) {
      p0[c]=a0[c]; p0[c+4]=a1[c];
      p1[c]=b0[c]; p1[c+4]=b1[c];
      p2[c]=d0[c]; p2[c+4]=d1[c];
      pbv[c]=e0[c]; pbv[c+4]=e1[c];
    }
  }

  bf16_t* zbase = Z + ((size_t)(b*TT + t0)*196 + hw)*CA_ + c0;
  #pragma unroll
  for (int i = 0; i < 8; i++) {
    bf16x8 zo;
    #pragma unroll
    for (int c = 0; c < 8; c++) {
      const float ym = (i > 0) ? y[i-1][c] : (th ? yedge[c] : 0.f);
      const float yp = (i < 7) ? y[i+1][c] : (th ? 0.f : yedge[c]);
      const float z  = y[i][c] + pbv[c] + p0[c]*ym + p1[c]*y[i][c] + p2[c]*yp;
      zo[c] = (bf16_t)z;
    }
    *(bf16x8*)(zbase + (size_t)i*rowstride) = zo;
  }
}

// ---------------- GEMM2: out[xrow,c] = x[xrow,c] + Z[tok,:] . fc2_w[c,:] + fc2_b[c] ----------------
// Same pipelined A-only-LDS structure; B = frag-linear W2f direct from L2. K=384, 12 steps.
__global__ __launch_bounds__(256) void gemm2_kernel(
    const bf16_t* __restrict__ Z, const bf16_t* __restrict__ W2f,
    const float* __restrict__ fc2b, const float* __restrict__ x,
    float* __restrict__ out) {
  __shared__ bf16_t Alds[3][4096];   // 8 KB each
  const int tid  = threadIdx.x;
  const int lane = tid & 63;
  const int wave = tid >> 6;
  const int bm = blockIdx.x, bn = blockIdx.y;

  const bf16_t* asrc0 = Z + (size_t)(bm*128 + (tid>>2))*CA_ + (tid&3)*8;
  const bf16_t* asrc1 = asrc0 + (size_t)64*CA_;
  const int off0 = tid*8;
  const int off1 = tid*8 + 2048;

  const int quad = lane >> 4;
  const int r16  = lane & 15;
  const int wm = (wave >> 1) * 64;
  const int wn = (wave & 1) * 64;

  // B frag base: f = ch*48 + (bn*8 + (wave&1)*4 + nt)
  const bf16_t* wb = W2f + ((size_t)(bn*8 + (wave & 1)*4))*512 + lane*8;

  f32x4 acc[4][4] = {};

#define G2_A(S, K) do { \
    gl_lds16(asrc0 + (K), &Alds[S][off0]); \
    gl_lds16(asrc1 + (K), &Alds[S][off1]); } while (0)
#define G2_B(CH) do { \
    bfr[0] = *(const bf16x8*)(wb + (size_t)((CH)*48 + 0)*512); \
    bfr[1] = *(const bf16x8*)(wb + (size_t)((CH)*48 + 1)*512); \
    bfr[2] = *(const bf16x8*)(wb + (size_t)((CH)*48 + 2)*512); \
    bfr[3] = *(const bf16x8*)(wb + (size_t)((CH)*48 + 3)*512); } while (0)
#define G2_M(S) do { bf16x8 af_[4]; \
    _Pragma("unroll") \
    for (int mt = 0; mt < 4; mt++) \
      af_[mt] = *(const bf16x8*)&Alds[S][(wm + mt*16 + r16)*32 + quad*8]; \
    _Pragma("unroll") \
    for (int mt = 0; mt < 4; mt++) \
      _Pragma("unroll") \
      for (int nt = 0; nt < 4; nt++) \
        acc[mt][nt] = __builtin_amdgcn_mfma_f32_16x16x32_bf16(af_[mt], bfr[nt], acc[mt][nt], 0, 0, 0); \
  } while (0)

  // prologue
  G2_A(0, 0);
  G2_A(1, 32);
  asm volatile("s_waitcnt vmcnt(2)" ::: "memory");
  SBAR();

  // main: i = 0..8 (issues A sets 2..10)
  #pragma unroll 1
  for (int ii = 0; ii < 3; ii++) {
    #pragma unroll
    for (int j = 0; j < 3; j++) {
      const int i = ii*3 + j;                  // buffer = j
      bf16x8 bfr[4];
      G2_B(i);
      __builtin_amdgcn_sched_barrier(0);
      G2_A((j + 2) % 3, (i + 2)*32);
      G2_M(j);
      asm volatile("s_waitcnt vmcnt(2)" ::: "memory");
      SBAR();
    }
  }
  { // i=9 (buf 0): issue A set 11
    bf16x8 bfr[4];
    G2_B(9);
    __builtin_amdgcn_sched_barrier(0);
    G2_A(2, 11*32);
    G2_M(0);
    asm volatile("s_waitcnt vmcnt(2)" ::: "memory");
    SBAR();
  }
  { // i=10 (buf 1)
    bf16x8 bfr[4];
    G2_B(10);
    __builtin_amdgcn_sched_barrier(0);
    G2_M(1);
    asm volatile("s_waitcnt vmcnt(0)" ::: "memory");
    SBAR();
  }
  { // i=11 (buf 2)
    bf16x8 bfr[4];
    G2_B(11);
    G2_M(2);
  }

  #pragma unroll
  for (int nt = 0; nt < 4; nt++) {
    const int col = bn*128 + wn + nt*16 + r16;
    const float bias = fc2b[col];
    #pragma unroll
    for (int mt = 0; mt < 4; mt++) {
      #pragma unroll
      for (int rg = 0; rg < 4; rg++) {
        const int tok = bm*128 + wm + mt*16 + quad*4 + rg;
        const int bt  = tok / 196;
        const size_t o = (size_t)(tok + bt + 1)*CIN + col;
        out[o] = x[o] + acc[mt][nt][rg] + bias;
      }
    }
  }
#undef G2_A
#undef G2_B
#undef G2_M
}

extern "C" void kernel_launch(void* const* d_in, const int* in_sizes, int n_in,
                              void* d_out, int out_size, void* d_ws, size_t ws_size,
                              hipStream_t stream) {
  (void)in_sizes; (void)n_in; (void)out_size; (void)ws_size;
  const float* x    = (const float*)d_in[0];
  const float* fc1w = (const float*)d_in[1];
  const float* fc1b = (const float*)d_in[2];
  const float* c1w  = (const float*)d_in[3];
  const float* c1b  = (const float*)d_in[4];
  const float* c2w  = (const float*)d_in[5];
  const float* c2b  = (const float*)d_in[6];
  const float* c3w  = (const float*)d_in[7];
  const float* c3b  = (const float*)d_in[8];
  const float* pw   = (const float*)d_in[9];
  const float* pb   = (const float*)d_in[10];
  const float* fc2w = (const float*)d_in[11];
  const float* fc2b = (const float*)d_in[12];
  float* out = (float*)d_out;

  char* ws = (char*)d_ws;
  bf16_t* W1f  = (bf16_t*)(ws);                    // 589824
  bf16_t* W2f  = (bf16_t*)(ws + 589824);           // 589824
  bf16_t* Wtb  = (bf16_t*)(ws + 1179648);          // 20736
  float*  beff = (float*) (ws + 1200384);          // 1536
  float*  pwt  = (float*) (ws + 1201920);          // 4608
  bf16_t* xb   = (bf16_t*)(ws + 1206528);          // 38535168 (dead after gemm1)
  bf16_t* Z    = (bf16_t*)(ws + 1206528);          // 19267584 (aliases xb; born in conv)
  bf16_t* H0   = (bf16_t*)(ws + 39741696);         // 19267584 -> total 59009280 bytes

  prep_weights_kernel<<<dim3(2), dim3(192), 0, stream>>>(
      c1w, c1b, c2w, c2b, c3w, c3b, pw, Wtb, beff, pwt);
  convert_w_kernel<<<dim3(4096), dim3(256), 0, stream>>>(fc1w, fc2w, x, out, W1f, W2f, xb);
  gemm1_kernel<<<dim3(196, 3), dim3(256), 0, stream>>>(xb, W1f, fc1b, H0);
  conv_kernel<<<dim3(784), dim3(192), 0, stream>>>(H0, Wtb, beff, pwt, pb, Z);
  gemm2_kernel<<<dim3(196, 6), dim3(256), 0, stream>>>(Z, W2f, fc2b, x, out);
}

// Round 9
// 262.574 us; speedup vs baseline: 1.0646x; 1.0143x over previous
//
#include <hip/hip_runtime.h>
#include <cstdint>

typedef __bf16 bf16_t;
typedef __bf16 bf16x4 __attribute__((ext_vector_type(4)));
typedef __bf16 bf16x8 __attribute__((ext_vector_type(8)));
typedef float f32x4 __attribute__((ext_vector_type(4)));

// ---- geometry constants ----
#define BT_   128
#define LTOK  197
#define CIN   768
#define CA_   384
#define TT    16
#define HH    14
#define NTOK  25088   // 128*196

__device__ __forceinline__ void gl_lds16(const void* g, void* l) {
  __builtin_amdgcn_global_load_lds(
      (const __attribute__((address_space(1))) unsigned int*)g,
      (__attribute__((address_space(3))) unsigned int*)l,
      16, 0, 0);
}

#define SBAR() do { __builtin_amdgcn_sched_barrier(0); \
                    __builtin_amdgcn_s_barrier(); \
                    __builtin_amdgcn_sched_barrier(0); } while (0)

// ---------------- fused prep + convert ----------------
// threads gid<384 additionally fold the 3 convs + identity into one 3x3x3 kernel.
// Streaming part: W -> bf16 FRAG-LINEAR, x token rows -> bf16 xb, CLS rows -> out.
// Frag layout (r5-verified): frag f holds a 16-col x 32-k B tile; lane l supplies
// B[col = cb*16 + (l&15)][k = ch*32 + (l>>4)*8 + j] -> elem f*512 + l*8 + j.
// W1f: f = ch*24 + cb (ch<24, cb<24).  W2f: f = ch*48 + cb (ch<12, cb<48).
__global__ __launch_bounds__(256) void convert_w_kernel(
    const float* __restrict__ fc1w, const float* __restrict__ fc2w,
    const float* __restrict__ x, float* __restrict__ out,
    bf16_t* __restrict__ W1f, bf16_t* __restrict__ W2f,
    bf16_t* __restrict__ xb,
    const float* __restrict__ c1w, const float* __restrict__ c1b,
    const float* __restrict__ c2w, const float* __restrict__ c2b,
    const float* __restrict__ c3w, const float* __restrict__ c3b,
    const float* __restrict__ projw,
    bf16_t* __restrict__ Wtb, float* __restrict__ beff, float* __restrict__ pwt) {
  const int gid = blockIdx.x*256 + threadIdx.x;
  if (gid < CA_) {
    const int a = gid;
    for (int dt = 0; dt < 3; dt++)
      for (int dh = 0; dh < 3; dh++)
        for (int dw = 0; dw < 3; dw++) {
          float v = c3w[a*27 + dt*9 + dh*3 + dw];
          if (dh == 1 && dw == 1) v += c1w[a*3 + dt];
          if (dt == 1)            v += c2w[a*9 + dh*3 + dw];
          v *= (1.0f/3.0f);
          if (dt == 1 && dh == 1 && dw == 1) v += 1.0f;   // + identity
          Wtb[((dt*3+dh)*3+dw)*CA_ + a] = (bf16_t)v;
        }
    beff[a] = (c1b[a] + c2b[a] + c3b[a]) * (1.0f/3.0f);
    pwt[0*CA_ + a] = projw[a*3 + 0];
    pwt[1*CA_ + a] = projw[a*3 + 1];
    pwt[2*CA_ + a] = projw[a*3 + 2];
  }

  const int NW1 = CA_*CIN/4;        // 73728 float4 units
  const int NW2 = CIN*CA_/4;        // 73728
  const int NX  = BT_*LTOK*CIN/4;   // 4841472
  const int total = NW1 + NW2 + NX;
  for (int i = gid; i < total; i += gridDim.x*256) {
    if (i < NW1) {
      int e = i*4, f = e >> 9, t = e & 511, l = t >> 3, jb = t & 7;
      int ch = f / 24, cb = f - ch*24;
      int col = cb*16 + (l & 15);
      int k   = ch*32 + ((l >> 4) << 3) + jb;
      float4 v = *(const float4*)(fc1w + (size_t)col*CIN + k);
      bf16x4 b; b[0]=(bf16_t)v.x; b[1]=(bf16_t)v.y; b[2]=(bf16_t)v.z; b[3]=(bf16_t)v.w;
      *(bf16x4*)(W1f + e) = b;
    } else if (i < NW1 + NW2) {
      int e = (i - NW1)*4, f = e >> 9, t = e & 511, l = t >> 3, jb = t & 7;
      int ch = f / 48, cb = f - ch*48;
      int col = cb*16 + (l & 15);
      int k   = ch*32 + ((l >> 4) << 3) + jb;
      float4 v = *(const float4*)(fc2w + (size_t)col*CA_ + k);
      bf16x4 b; b[0]=(bf16_t)v.x; b[1]=(bf16_t)v.y; b[2]=(bf16_t)v.z; b[3]=(bf16_t)v.w;
      *(bf16x4*)(W2f + e) = b;
    } else {
      int j = i - NW1 - NW2;        // float4 index into x
      int row = j / 192;            // 192 float4 per 768-ch row
      int c4  = j - row*192;
      int l   = row % 197;
      float4 v = ((const float4*)x)[(size_t)j];
      if (l == 0) {
        ((float4*)out)[(size_t)j] = v;   // CLS residual passthrough
      } else {
        int tok = (row/197)*196 + (l - 1);
        bf16x4 b; b[0]=(bf16_t)v.x; b[1]=(bf16_t)v.y; b[2]=(bf16_t)v.z; b[3]=(bf16_t)v.w;
        *(bf16x4*)(xb + (size_t)tok*CIN + c4*4) = b;
      }
    }
  }
}

// ---------------- GEMM1: H0[tok,a] = bf16( xb[tok,:] . fc1_w[a,:] + fc1_b[a] ) ----------------
// M=64 x N=128 tile (grid 392x3 = 1176 blocks for TLP), A-only LDS (3 x 4KB,
// prefetch distance 2, counted vmcnt), B frag-linear direct from L2 into regs,
// issued FIRST each step so the compiler's B-wait retires gl_lds(i+1) in order.
__global__ __launch_bounds__(256) void gemm1_kernel(
    const bf16_t* __restrict__ xb, const bf16_t* __restrict__ W1f,
    const float* __restrict__ fc1b, bf16_t* __restrict__ H0) {
  __shared__ bf16_t Alds[3][2048];   // 4 KB each: [64][32]
  const int tid  = threadIdx.x;
  const int lane = tid & 63;
  const int wave = tid >> 6;
  const int bm = blockIdx.x, bn = blockIdx.y;

  const bf16_t* asrc = xb + (size_t)(bm*64 + (tid>>2))*CIN + (tid&3)*8;
  const int aoff = tid*8;   // == row*32 + g*8 : linear [64][32]

  const int quad = lane >> 4;
  const int r16  = lane & 15;

  // B frag base: f = ch*24 + (bn*8 + wave*2 + nt)
  const bf16_t* wb = W1f + ((size_t)(bn*8 + wave*2))*512 + lane*8;

  f32x4 acc[4][2] = {};

#define G1_A(S, K) gl_lds16(asrc + (K), &Alds[S][aoff])
#define G1_B(CH) do { \
    bfr[0] = *(const bf16x8*)(wb + (size_t)((CH)*24 + 0)*512); \
    bfr[1] = *(const bf16x8*)(wb + (size_t)((CH)*24 + 1)*512); } while (0)
#define G1_M(S) do { bf16x8 af_[4]; \
    _Pragma("unroll") \
    for (int mt = 0; mt < 4; mt++) \
      af_[mt] = *(const bf16x8*)&Alds[S][(mt*16 + r16)*32 + quad*8]; \
    _Pragma("unroll") \
    for (int mt = 0; mt < 4; mt++) \
      _Pragma("unroll") \
      for (int nt = 0; nt < 2; nt++) \
        acc[mt][nt] = __builtin_amdgcn_mfma_f32_16x16x32_bf16(af_[mt], bfr[nt], acc[mt][nt], 0, 0, 0); \
  } while (0)

  // prologue: A sets 0,1 in flight; wait set 0 only
  G1_A(0, 0);
  G1_A(1, 32);
  asm volatile("s_waitcnt vmcnt(1)" ::: "memory");
  SBAR();

  // main: i = 0..20 (issues A sets 2..22)
  #pragma unroll 1
  for (int ii = 0; ii < 7; ii++) {
    #pragma unroll
    for (int j = 0; j < 3; j++) {
      const int i = ii*3 + j;                  // buffer = j
      bf16x8 bfr[2];
      G1_B(i);                                 // B first (in-order retire carrier)
      __builtin_amdgcn_sched_barrier(0);
      G1_A((j + 2) % 3, (i + 2)*32);           // then A set i+2
      G1_M(j);                                 // waits B(i) -> retires gl(i+1)
      asm volatile("s_waitcnt vmcnt(1)" ::: "memory");
      SBAR();
    }
  }
  { // i=21 (buf 0): issue A set 23
    bf16x8 bfr[2];
    G1_B(21);
    __builtin_amdgcn_sched_barrier(0);
    G1_A(2, 23*32);
    G1_M(0);
    asm volatile("s_waitcnt vmcnt(1)" ::: "memory");
    SBAR();
  }
  { // i=22 (buf 1)
    bf16x8 bfr[2];
    G1_B(22);
    __builtin_amdgcn_sched_barrier(0);
    G1_M(1);
    asm volatile("s_waitcnt vmcnt(0)" ::: "memory");
    SBAR();
  }
  { // i=23 (buf 2)
    bf16x8 bfr[2];
    G1_B(23);
    G1_M(2);
  }

  #pragma unroll
  for (int nt = 0; nt < 2; nt++) {
    const int col = bn*128 + wave*32 + nt*16 + r16;
    const float bias = fc1b[col];
    #pragma unroll
    for (int mt = 0; mt < 4; mt++) {
      const int row0 = bm*64 + mt*16 + quad*4;
      #pragma unroll
      for (int rg = 0; rg < 4; rg++)
        H0[(size_t)(row0 + rg)*CA_ + col] = (bf16_t)(acc[mt][nt][rg] + bias);
    }
  }
#undef G1_A
#undef G1_B
#undef G1_M
}

// ---------------- fused conv v4: register-local temporal scatter, XCD-swizzled ----------------
__global__ __launch_bounds__(192) void conv_kernel(
    const bf16_t* __restrict__ H0,
    const bf16_t* __restrict__ Wtb,   // [27][384] bf16
    const float* __restrict__ beff,   // [384]
    const float* __restrict__ pwt,    // [3][384]
    const float* __restrict__ pb,     // [384]
    bf16_t* __restrict__ Z) {
  __shared__ bf16_t Wlds[27*CA_];     // 20736 B
  __shared__ float  ybuf[2][2][CA_];  // 6144 B

  const int tid = threadIdx.x;
  {
    const uint4* src = (const uint4*)Wtb;
    uint4* dst = (uint4*)Wlds;
    #pragma unroll
    for (int i = 0; i < 7; i++) {
      int idx = tid + i*192;
      if (idx < 27*CA_/8) dst[idx] = src[idx];   // 1296 x 16B
    }
  }

  const int blk  = blockIdx.x;       // 0..783
  const int b    = blk & 7;
  const int pair = blk >> 3;         // 0..97
  const int cg   = tid % 48;
  const int ct   = tid / 48;         // 0..3
  const int col  = ct >> 1;
  const int th   = ct & 1;
  const int hw   = pair*2 + col;     // 0..195
  const int h    = hw / HH, w = hw % HH;
  const int c0   = cg * 8;
  const int t0   = th * 8;

  // init y with effective bias
  float y[8][8];
  {
    f32x4 bv0 = *(const f32x4*)(beff + c0);
    f32x4 bv1 = *(const f32x4*)(beff + c0 + 4);
    #pragma unroll
    for (int i = 0; i < 8; i++) {
      #pragma unroll
      for (int c = 0; c < 4; c++) { y[i][c] = bv0[c]; y[i][c+4] = bv1[c]; }
    }
  }

  __syncthreads();   // Wlds ready

  const size_t rowstride = (size_t)196*CA_;   // elements per t-step
  const bf16_t* base_t0 = H0 + ((size_t)(b*TT + t0)*196)*CA_ + c0;
  const int tau_e_off = th ? -1 : 8;          // the one extra valid tau (relative to t0)

  for (int j = 0; j < 9; j++) {
    const int dh = j / 3, dw = j - dh*3;
    const int h2 = h + dh - 1, w2 = w + dw - 1;
    const bool ok = ((unsigned)h2 < HH) && ((unsigned)w2 < HH);
    const int sp = ok ? (h2*HH + w2) : hw;    // clamped, always in-bounds
    const float m = ok ? 1.0f : 0.0f;

    const bf16x8 wv0 = *(const bf16x8*)&Wlds[(0*9+j)*CA_ + c0];
    const bf16x8 wv1 = *(const bf16x8*)&Wlds[(1*9+j)*CA_ + c0];
    const bf16x8 wv2 = *(const bf16x8*)&Wlds[(2*9+j)*CA_ + c0];
    float mw0[8], mw1[8], mw2[8];
    #pragma unroll
    for (int c = 0; c < 8; c++) {
      mw0[c] = m * (float)wv0[c];
      mw1[c] = m * (float)wv1[c];
      mw2[c] = m * (float)wv2[c];
    }

    const bf16_t* tp = base_t0 + (size_t)sp*CA_;
    bf16x8 gv[8];
    #pragma unroll
    for (int i = 0; i < 8; i++)
      gv[i] = *(const bf16x8*)(tp + (ptrdiff_t)i*(ptrdiff_t)rowstride);
    const bf16x8 ge = *(const bf16x8*)(tp + (ptrdiff_t)tau_e_off*(ptrdiff_t)rowstride);

    // interior taus: tau = t0+i contributes to y[i-1] (w2), y[i] (w1), y[i+1] (w0)
    #pragma unroll
    for (int i = 0; i < 8; i++) {
      float gf[8];
      #pragma unroll
      for (int c = 0; c < 8; c++) gf[c] = (float)gv[i][c];
      #pragma unroll
      for (int c = 0; c < 8; c++) y[i][c] += gf[c]*mw1[c];
      if (i > 0) {
        #pragma unroll
        for (int c = 0; c < 8; c++) y[i-1][c] += gf[c]*mw2[c];
      }
      if (i < 7) {
        #pragma unroll
        for (int c = 0; c < 8; c++) y[i+1][c] += gf[c]*mw0[c];
      }
    }
    // edge tau: th=0 -> tau=t0+8 feeds y[7] via w2 ; th=1 -> tau=t0-1 feeds y[0] via w0
    {
      float gf[8];
      #pragma unroll
      for (int c = 0; c < 8; c++) gf[c] = (float)ge[c];
      if (th) {
        #pragma unroll
        for (int c = 0; c < 8; c++) y[0][c] += gf[c]*mw0[c];
      } else {
        #pragma unroll
        for (int c = 0; c < 8; c++) y[7][c] += gf[c]*mw2[c];
      }
    }
  }

  // exchange the boundary y between t-halves (for the temporal proj)
  #pragma unroll
  for (int c = 0; c < 8; c++) ybuf[col][th][c0+c] = th ? y[0][c] : y[7][c];
  __syncthreads();
  float yedge[8];
  #pragma unroll
  for (int c = 0; c < 8; c++) yedge[c] = ybuf[col][1-th][c0+c];

  // proj weights
  float p0[8], p1[8], p2[8], pbv[8];
  {
    f32x4 a0 = *(const f32x4*)(pwt + 0*CA_ + c0), a1 = *(const f32x4*)(pwt + 0*CA_ + c0 + 4);
    f32x4 b0 = *(const f32x4*)(pwt + 1*CA_ + c0), b1 = *(const f32x4*)(pwt + 1*CA_ + c0 + 4);
    f32x4 d0 = *(const f32x4*)(pwt + 2*CA_ + c0), d1 = *(const f32x4*)(pwt + 2*CA_ + c0 + 4);
    f32x4 e0 = *(const f32x4*)(pb + c0),          e1 = *(const f32x4*)(pb + c0 + 4);
    #pragma unroll
    for (int c = 0; c < 4; c++) {
      p0[c]=a0[c]; p0[c+4]=a1[c];
      p1[c]=b0[c]; p1[c+4]=b1[c];
      p2[c]=d0[c]; p2[c+4]=d1[c];
      pbv[c]=e0[c]; pbv[c+4]=e1[c];
    }
  }

  bf16_t* zbase = Z + ((size_t)(b*TT + t0)*196 + hw)*CA_ + c0;
  #pragma unroll
  for (int i = 0; i < 8; i++) {
    bf16x8 zo;
    #pragma unroll
    for (int c = 0; c < 8; c++) {
      const float ym = (i > 0) ? y[i-1][c] : (th ? yedge[c] : 0.f);
      const float yp = (i < 7) ? y[i+1][c] : (th ? 0.f : yedge[c]);
      const float z  = y[i][c] + pbv[c] + p0[c]*ym + p1[c]*y[i][c] + p2[c]*yp;
      zo[c] = (bf16_t)z;
    }
    *(bf16x8*)(zbase + (size_t)i*rowstride) = zo;
  }
}

// ---------------- GEMM2: out[xrow,c] = x[xrow,c] + Z[tok,:] . fc2_w[c,:] + fc2_b[c] ----------------
// M=64 x N=128 tile (grid 392x6 = 2352 blocks), same pipelined A-only-LDS structure;
// B = frag-linear W2f direct from L2. K=384, 12 steps.
__global__ __launch_bounds__(256) void gemm2_kernel(
    const bf16_t* __restrict__ Z, const bf16_t* __restrict__ W2f,
    const float* __restrict__ fc2b, const float* __restrict__ x,
    float* __restrict__ out) {
  __shared__ bf16_t Alds[3][2048];   // 4 KB each
  const int tid  = threadIdx.x;
  const int lane = tid & 63;
  const int wave = tid >> 6;
  const int bm = blockIdx.x, bn = blockIdx.y;

  const bf16_t* asrc = Z + (size_t)(bm*64 + (tid>>2))*CA_ + (tid&3)*8;
  const int aoff = tid*8;

  const int quad = lane >> 4;
  const int r16  = lane & 15;

  // B frag base: f = ch*48 + (bn*8 + wave*2 + nt)
  const bf16_t* wb = W2f + ((size_t)(bn*8 + wave*2))*512 + lane*8;

  f32x4 acc[4][2] = {};

#define G2_A(S, K) gl_lds16(asrc + (K), &Alds[S][aoff])
#define G2_B(CH) do { \
    bfr[0] = *(const bf16x8*)(wb + (size_t)((CH)*48 + 0)*512); \
    bfr[1] = *(const bf16x8*)(wb + (size_t)((CH)*48 + 1)*512); } while (0)
#define G2_M(S) do { bf16x8 af_[4]; \
    _Pragma("unroll") \
    for (int mt = 0; mt < 4; mt++) \
      af_[mt] = *(const bf16x8*)&Alds[S][(mt*16 + r16)*32 + quad*8]; \
    _Pragma("unroll") \
    for (int mt = 0; mt < 4; mt++) \
      _Pragma("unroll") \
      for (int nt = 0; nt < 2; nt++) \
        acc[mt][nt] = __builtin_amdgcn_mfma_f32_16x16x32_bf16(af_[mt], bfr[nt], acc[mt][nt], 0, 0, 0); \
  } while (0)

  // prologue
  G2_A(0, 0);
  G2_A(1, 32);
  asm volatile("s_waitcnt vmcnt(1)" ::: "memory");
  SBAR();

  // main: i = 0..8 (issues A sets 2..10)
  #pragma unroll 1
  for (int ii = 0; ii < 3; ii++) {
    #pragma unroll
    for (int j = 0; j < 3; j++) {
      const int i = ii*3 + j;                  // buffer = j
      bf16x8 bfr[2];
      G2_B(i);
      __builtin_amdgcn_sched_barrier(0);
      G2_A((j + 2) % 3, (i + 2)*32);
      G2_M(j);
      asm volatile("s_waitcnt vmcnt(1)" ::: "memory");
      SBAR();
    }
  }
  { // i=9 (buf 0): issue A set 11
    bf16x8 bfr[2];
    G2_B(9);
    __builtin_amdgcn_sched_barrier(0);
    G2_A(2, 11*32);
    G2_M(0);
    asm volatile("s_waitcnt vmcnt(1)" ::: "memory");
    SBAR();
  }
  { // i=10 (buf 1)
    bf16x8 bfr[2];
    G2_B(10);
    __builtin_amdgcn_sched_barrier(0);
    G2_M(1);
    asm volatile("s_waitcnt vmcnt(0)" ::: "memory");
    SBAR();
  }
  { // i=11 (buf 2)
    bf16x8 bfr[2];
    G2_B(11);
    G2_M(2);
  }

  #pragma unroll
  for (int nt = 0; nt < 2; nt++) {
    const int col = bn*128 + wave*32 + nt*16 + r16;
    const float bias = fc2b[col];
    #pragma unroll
    for (int mt = 0; mt < 4; mt++) {
      #pragma unroll
      for (int rg = 0; rg < 4; rg++) {
        const int tok = bm*64 + mt*16 + quad*4 + rg;
        const int bt  = tok / 196;
        const size_t o = (size_t)(tok + bt + 1)*CIN + col;
        out[o] = x[o] + acc[mt][nt][rg] + bias;
      }
    }
  }
#undef G2_A
#undef G2_B
#undef G2_M
}

extern "C" void kernel_launch(void* const* d_in, const int* in_sizes, int n_in,
                              void* d_out, int out_size, void* d_ws, size_t ws_size,
                              hipStream_t stream) {
  (void)in_sizes; (void)n_in; (void)out_size; (void)ws_size;
  const float* x    = (const float*)d_in[0];
  const float* fc1w = (const float*)d_in[1];
  const float* fc1b = (const float*)d_in[2];
  const float* c1w  = (const float*)d_in[3];
  const float* c1b  = (const float*)d_in[4];
  const float* c2w  = (const float*)d_in[5];
  const float* c2b  = (const float*)d_in[6];
  const float* c3w  = (const float*)d_in[7];
  const float* c3b  = (const float*)d_in[8];
  const float* pw   = (const float*)d_in[9];
  const float* pb   = (const float*)d_in[10];
  const float* fc2w = (const float*)d_in[11];
  const float* fc2b = (const float*)d_in[12];
  float* out = (float*)d_out;

  char* ws = (char*)d_ws;
  bf16_t* W1f  = (bf16_t*)(ws);                    // 589824
  bf16_t* W2f  = (bf16_t*)(ws + 589824);           // 589824
  bf16_t* Wtb  = (bf16_t*)(ws + 1179648);          // 20736
  float*  beff = (float*) (ws + 1200384);          // 1536
  float*  pwt  = (float*) (ws + 1201920);          // 4608
  bf16_t* xb   = (bf16_t*)(ws + 1206528);          // 38535168 (dead after gemm1)
  bf16_t* Z    = (bf16_t*)(ws + 1206528);          // 19267584 (aliases xb; born in conv)
  bf16_t* H0   = (bf16_t*)(ws + 39741696);         // 19267584 -> total 59009280 bytes

  convert_w_kernel<<<dim3(4096), dim3(256), 0, stream>>>(
      fc1w, fc2w, x, out, W1f, W2f, xb,
      c1w, c1b, c2w, c2b, c3w, c3b, pw, Wtb, beff, pwt);
  gemm1_kernel<<<dim3(392, 3), dim3(256), 0, stream>>>(xb, W1f, fc1b, H0);
  conv_kernel<<<dim3(784), dim3(192), 0, stream>>>(H0, Wtb, beff, pwt, pb, Z);
  gemm2_kernel<<<dim3(392, 6), dim3(256), 0, stream>>>(Z, W2f, fc2b, x, out);
}